// Round 6
// baseline (175.440 us; speedup 1.0000x reference)
//
#include <hip/hip_runtime.h>

#define IMG 512
#define PAD 5
#define KW  11
#define SH  64                 // output rows per block strip
#define WCOLS 64               // output cols per wave
#define NWAVES 4
#define BW (WCOLS * NWAVES)    // 256 cols per block
#define STG (WCOLS + 2 * PAD)  // 74 staged cols per wave
#define NPLANES 48
#define NCHUNK 7               // 7*11 = 77 >= max 74 input rows

// Wave-independent row-streaming SSIM.
// Register-ring vertical blur (4 quantities x 11 slots, compile-time slots
// via 11-phase unroll). Round-5 evidence: VGPR_Count=48 with ~75 live regs
// => allocator demoted the ring (AGPR/scratch tax ~2x VALU). Fix:
// amdgpu_waves_per_eu(3,3) pins target occupancy at the grid's actual
// 3 waves/EU -> budget ~170 arch VGPRs, ring stays in VGPRs.
__global__
__attribute__((amdgpu_flat_work_group_size(256, 256), amdgpu_waves_per_eu(3, 3)))
void ssim_wave_kernel(
    const float* __restrict__ img1,
    const float* __restrict__ img2,
    double* __restrict__ accum)
{
    __shared__ float2 sbuf[NWAVES][STG + 1];   // ~2.4 KB

    // Normalized 1D gaussian weights -> SGPRs.
    float w[KW];
    {
        float wv[KW];
        float s = 0.f;
#pragma unroll
        for (int i = 0; i < KW; ++i) {
            float d = (float)(i - PAD);
            wv[i] = expf(-(d * d) / 4.5f);     // 2*sigma^2 = 4.5
            s += wv[i];
        }
#pragma unroll
        for (int i = 0; i < KW; ++i)
            w[i] = __uint_as_float(
                __builtin_amdgcn_readfirstlane(__float_as_uint(wv[i] / s)));
    }

    const int tid   = threadIdx.x;
    const int wv_id = tid >> 6;
    const int lane  = tid & 63;
    const int plane = blockIdx.z;
    const int wc0   = blockIdx.x * BW + wv_id * WCOLS;
    const int y0    = blockIdx.y * SH;

    const float* __restrict__ A = img1 + (size_t)plane * (IMG * IMG);
    const float* __restrict__ B = img2 + (size_t)plane * (IMG * IMG);
    float2* lbuf = &sbuf[wv_id][0];

    // Per-thread column addressing (constant across rows).
    const int c0  = wc0 - PAD + lane;            // main staged col
    const int cc0 = min(max(c0, 0), IMG - 1);
    const float m0 = (c0 >= 0 && c0 < IMG) ? 1.f : 0.f;
    const int c1  = wc0 + (WCOLS - PAD) + lane;  // edge staged col (lane<10)
    const int cc1 = min(c1, IMG - 1);
    const float m1 = (c1 < IMG) ? 1.f : 0.f;

    const int ystart = max(y0 - PAD, 0);
    const int yend   = min(y0 + SH + PAD, IMG);

    // Vertical pending accumulators: 4 quantities x 11 slots, registers only.
    float acc0[KW], acc1[KW], acc2[KW], acc3[KW];
#pragma unroll
    for (int j = 0; j < KW; ++j) {
        acc0[j] = 0.f; acc1[j] = 0.f; acc2[j] = 0.f; acc3[j] = 0.f;
    }

    const float C1v = 1e-4f;
    const float C2v = 9e-4f;
    float local = 0.f;

    // Prefetch first row.
    const float* rowA = A + (size_t)ystart * IMG;
    const float* rowB = B + (size_t)ystart * IMG;
    float pa0 = rowA[cc0], pb0 = rowB[cc0];
    float pa1 = rowA[cc1], pb1 = rowB[cc1];

    int y = ystart;

    // SSIM evaluation of one completed slot (compile-time slot index).
#define SSIM_EMIT(sd)                                                          \
    {                                                                          \
        const float mu1 = acc0[sd], mu2 = acc1[sd];                            \
        const float xs  = acc2[sd], x12 = acc3[sd];                            \
        const float mu1s = mu1 * mu1, mu2s = mu2 * mu2;                        \
        const float m12 = mu1 * mu2;                                           \
        const float num = (2.f * m12 + C1v) * (2.f * (x12 - m12) + C2v);       \
        const float den = (mu1s + mu2s + C1v) *                                \
                          ((xs - mu1s - mu2s) + C2v);                          \
        local += num * __builtin_amdgcn_rcpf(den);                             \
    }

#define SSIM_PHASE(p)                                                          \
    if (y < yend) {                                                            \
        /* stage current row (regs -> LDS, masked zeros for x-pad) */          \
        lbuf[lane] = make_float2(pa0 * m0, pb0 * m0);                          \
        if (lane < 2 * PAD)                                                    \
            lbuf[WCOLS + lane] = make_float2(pa1 * m1, pb1 * m1);              \
        /* prefetch next row into regs (latency hidden under compute) */       \
        if (y + 1 < yend) {                                                    \
            rowA += IMG; rowB += IMG;                                          \
            pa0 = rowA[cc0]; pb0 = rowB[cc0];                                  \
            pa1 = rowA[cc1]; pb1 = rowB[cc1];                                  \
        }                                                                      \
        /* horizontal 11-tap blur of {a, b, a^2+b^2, ab} */                    \
        float h0 = 0.f, h1 = 0.f, h2 = 0.f, h3 = 0.f;                          \
        _Pragma("unroll")                                                      \
        for (int k = 0; k < KW; ++k) {                                         \
            const float2 ab = lbuf[lane + k];                                  \
            const float a = ab.x, b = ab.y;                                    \
            float sq = a * a;                                                  \
            sq = fmaf(b, b, sq);                                               \
            h0 += w[k] * a;                                                    \
            h1 += w[k] * b;                                                    \
            h2 += w[k] * sq;                                                   \
            h3 += w[k] * (a * b);                                              \
        }                                                                      \
        /* vertical scatter: input y -> outputs r=y-5+j, slot=(r-ystart)%11 */ \
        _Pragma("unroll")                                                      \
        for (int j = 0; j < KW; ++j) {                                         \
            const int sl = ((p) + 6 + j) % KW;                                 \
            const float wj = w[10 - j];                                        \
            acc0[sl] += wj * h0;                                               \
            acc1[sl] += wj * h1;                                               \
            acc2[sl] += wj * h2;                                               \
            acc3[sl] += wj * h3;                                               \
        }                                                                      \
        /* emit completed output row r = y-5 */                                \
        {                                                                      \
            const int sd = ((p) + 6) % KW;                                     \
            const int r = y - PAD;                                             \
            if (r >= y0) SSIM_EMIT(sd);                                        \
            acc0[sd] = 0.f; acc1[sd] = 0.f; acc2[sd] = 0.f; acc3[sd] = 0.f;    \
        }                                                                      \
        ++y;                                                                   \
    }

#pragma unroll 1
    for (int chunk = 0; chunk < NCHUNK; ++chunk) {
        SSIM_PHASE(0) SSIM_PHASE(1) SSIM_PHASE(2) SSIM_PHASE(3)
        SSIM_PHASE(4) SSIM_PHASE(5) SSIM_PHASE(6) SSIM_PHASE(7)
        SSIM_PHASE(8) SSIM_PHASE(9) SSIM_PHASE(10)
    }
#undef SSIM_PHASE

    // Bottom strip: rows 507..511 truncate at y=511; flush their slots.
    // ystart=443 -> slot(r)=(r-443)%11: 507->9, 508->10, 509->0, 510->1, 511->2.
    if (blockIdx.y == (IMG / SH - 1)) {
        SSIM_EMIT(9) SSIM_EMIT(10) SSIM_EMIT(0) SSIM_EMIT(1) SSIM_EMIT(2)
    }
#undef SSIM_EMIT

    // Per-wave reduction + one atomic per wave.
#pragma unroll
    for (int off = 32; off > 0; off >>= 1)
        local += __shfl_down(local, off);
    if (lane == 0)
        atomicAdd(accum, (double)local);
}

__global__ void ssim_finalize_kernel(const double* __restrict__ accum,
                                     float* __restrict__ out)
{
    const double N = (double)NPLANES * IMG * IMG;
    out[0] = (float)(1.0 - accum[0] / N);
}

extern "C" void kernel_launch(void* const* d_in, const int* in_sizes, int n_in,
                              void* d_out, int out_size, void* d_ws, size_t ws_size,
                              hipStream_t stream) {
    const float* img1 = (const float*)d_in[0];
    const float* img2 = (const float*)d_in[1];
    float* out = (float*)d_out;
    double* accum = (double*)d_ws;   // 8 bytes used

    // d_ws is poisoned 0xAA before every call — zero the accumulator.
    hipMemsetAsync(accum, 0, sizeof(double), stream);

    dim3 grid(IMG / BW, IMG / SH, NPLANES);   // 2 x 8 x 48 = 768 blocks
    ssim_wave_kernel<<<grid, BW, 0, stream>>>(img1, img2, accum);
    ssim_finalize_kernel<<<1, 1, 0, stream>>>(accum, out);
}